// Round 7
// baseline (222.843 us; speedup 1.0000x reference)
//
#include <hip/hip_runtime.h>
#include <hip/hip_bf16.h>

#define N_NODES 100000
#define N_EDGES 800000
#define F 128          // IN_FEATS == N_HIDDEN
#define C_OUT 64       // N_CLASSES
#define CAP 48         // per-node bucket capacity (Poisson(8): P(deg>=48)~1e-25)
#define DUMMY N_NODES  // dummy src index -> zero row appended to xb (ws path)

typedef __bf16 bf16x8 __attribute__((ext_vector_type(8)));
typedef __bf16 bf16x4 __attribute__((ext_vector_type(4)));
typedef __bf16 bf16x2 __attribute__((ext_vector_type(2)));
typedef float f32x4 __attribute__((ext_vector_type(4)));

// ---------------------------------------------------------------------------
// prep = conv(x->bf16) + edge bucket fill + weight swizzle (+ zero dummy row).
// Grid 3125 x 256 = 800,000 threads exactly.
// ---------------------------------------------------------------------------
__global__ __launch_bounds__(256) void prep(const float* __restrict__ x,
                                            const int* __restrict__ src,
                                            const int* __restrict__ dst,
                                            float* __restrict__ emb,
                                            int* __restrict__ cnt,
                                            const float* __restrict__ Wn,
                                            const float* __restrict__ Wo,
                                            __bf16* __restrict__ Wn_s,
                                            __bf16* __restrict__ Wo_s,
                                            __bf16* __restrict__ xb,
                                            int zero_dummy) {
    const int t = blockIdx.x * 256 + threadIdx.x;

    // ---- conv: 4 strided float4 -> bf16x4 ----
#pragma unroll
    for (int k = 0; k < 4; k++) {
        const int i = k * 800000 + t;
        const float4 v = ((const float4*)x)[i];
        bf16x4 b;
        b.x = (__bf16)v.x; b.y = (__bf16)v.y; b.z = (__bf16)v.z; b.w = (__bf16)v.w;
        *(bf16x4*)(xb + (size_t)i * 4) = b;
    }

    // ---- zero dummy row (row N_NODES, 256 B) for gather index padding ----
    if (zero_dummy && t < 32) {
        int2 z = make_int2(0, 0);
        ((int2*)(xb + (size_t)N_NODES * F))[t] = z;
    }

    // ---- fill: one edge per thread; bucket = first 48 ints of dst's emb row
    const int d = dst[t];
    const int slot = atomicAdd(cnt + d, 1);
    if (slot < CAP) ((int*)(emb + (size_t)d * F))[slot] = src[t];

    // ---- swizzle: weights -> bf16 B-fragment-linear (lane l holds
    //      B[k=(l>>4)*8+j][n=l&15]); group g=(nb*4+kb)*64+lane ----
    if (t < 3072) {
        const float* W;
        __bf16* Ws;
        int g, ncols;
        if (t < 2048) { W = Wn; Ws = Wn_s; g = t;        ncols = 128; }
        else          { W = Wo; Ws = Wo_s; g = t - 2048; ncols = 64;  }
        const int l = g & 63;
        const int kb = (g >> 6) & 3;
        const int nb = g >> 8;
        const int q = l >> 4, m = l & 15;
        const int n = nb * 16 + m;
        __bf16 v[8];
#pragma unroll
        for (int j = 0; j < 8; j++) {
            const int k = kb * 32 + q * 8 + j;
            v[j] = (__bf16)W[(size_t)k * ncols + n];
        }
        *(bf16x8*)(Ws + (size_t)g * 8) = *(bf16x8*)v;
    }
}

// ---------------------------------------------------------------------------
// sage_fused: 4 independent waves/block, 16 nodes/wave, no barriers.
//   gather: 8-node interleave, bucket int4s read raw (incl. garbage tail
//   slots) and padded IN REGISTER with cndmask->DUMMY (zero row). No pad
//   stores, no vmcnt(0) drains. Up to 32 row loads in flight per wave.
//   -> h bf16 LDS -> MFMA GEMM1 -> relu -> f32 LDS transpose -> coalesced emb
//   stores + A2-frags from same LDS -> MFMA GEMM2 -> coalesced out stores.
// A-frag: lane holds A[m=lane&15][k=(lane>>4)*8+j]; C/D: row=(lane>>4)*4+r,
// col=lane&15 (m89-verified).
// ---------------------------------------------------------------------------
__global__ __launch_bounds__(256, 4) void sage_fused(const __bf16* __restrict__ xb,
                                                     const int* __restrict__ cnt,
                                                     const __bf16* __restrict__ Wn_s,
                                                     const __bf16* __restrict__ Wo_s,
                                                     const float* __restrict__ bn,
                                                     const float* __restrict__ bo,
                                                     float* __restrict__ out,
                                                     float* emb) {
    __shared__ __align__(16) __bf16 Hs[4][16][136];  // 4352 B per wave
    const int w = threadIdx.x >> 6;
    const int lane = threadIdx.x & 63;
    const int node0 = (blockIdx.x * 4 + w) * 16;
    if (node0 >= N_NODES) return;  // 1563*4 = 6252 waves; 2 idle
    const int q = lane >> 4, m = lane & 15;
    __bf16(*H)[136] = Hs[w];

    // ---- gather: two batches of 8 nodes, fully interleaved ----
#pragma unroll
    for (int b = 0; b < 16; b += 8) {
        const int na = node0 + b;
        const int4 d0 = *(const int4*)(cnt + na);      // 16B-aligned (na%16 in {0,8})
        const int4 d1 = *(const int4*)(cnt + na + 4);
        int deg[8], n[8], p[8];
        deg[0] = __builtin_amdgcn_readfirstlane(d0.x);
        deg[1] = __builtin_amdgcn_readfirstlane(d0.y);
        deg[2] = __builtin_amdgcn_readfirstlane(d0.z);
        deg[3] = __builtin_amdgcn_readfirstlane(d0.w);
        deg[4] = __builtin_amdgcn_readfirstlane(d1.x);
        deg[5] = __builtin_amdgcn_readfirstlane(d1.y);
        deg[6] = __builtin_amdgcn_readfirstlane(d1.z);
        deg[7] = __builtin_amdgcn_readfirstlane(d1.w);
        const int* bk[8];
        float2 acc[8];
        int pmax = 0;
#pragma unroll
        for (int i = 0; i < 8; i++) {
            n[i] = deg[i] < CAP ? deg[i] : CAP;
            p[i] = (n[i] + 3) & ~3;
            pmax = p[i] > pmax ? p[i] : pmax;
            bk[i] = (const int*)(emb + (size_t)(na + i) * F);
            const bf16x2 s = *(const bf16x2*)(xb + (size_t)(na + i) * F + 2 * lane);
            acc[i].x = (float)s.x;
            acc[i].y = (float)s.y;
        }
        for (int j = 0; j < pmax; j += 4) {
            int idx[8][4];
            // phase 1: issue bucket int4 loads + in-register DUMMY padding
#pragma unroll
            for (int i = 0; i < 8; i++) {
                if (j < p[i]) {
                    const int4 s4 = *(const int4*)(bk[i] + j);  // tail slots garbage, replaced below
                    idx[i][0] = (j + 0 < n[i]) ? s4.x : DUMMY;
                    idx[i][1] = (j + 1 < n[i]) ? s4.y : DUMMY;
                    idx[i][2] = (j + 2 < n[i]) ? s4.z : DUMMY;
                    idx[i][3] = (j + 3 < n[i]) ? s4.w : DUMMY;
                }
            }
            // phase 2: issue up to 32 row loads
            bf16x2 v[8][4];
#pragma unroll
            for (int i = 0; i < 8; i++) {
                if (j < p[i]) {
#pragma unroll
                    for (int k = 0; k < 4; k++)
                        v[i][k] = *(const bf16x2*)(xb + (size_t)idx[i][k] * F + 2 * lane);
                }
            }
            // phase 3: accumulate
#pragma unroll
            for (int i = 0; i < 8; i++) {
                if (j < p[i]) {
                    acc[i].x += (float)v[i][0].x + (float)v[i][1].x +
                                (float)v[i][2].x + (float)v[i][3].x;
                    acc[i].y += (float)v[i][0].y + (float)v[i][1].y +
                                (float)v[i][2].y + (float)v[i][3].y;
                }
            }
        }
#pragma unroll
        for (int i = 0; i < 8; i++) {
            const float inv = 1.0f / (float)(deg[i] + 1);
            bf16x2 h;
            h.x = (__bf16)(acc[i].x * inv);
            h.y = (__bf16)(acc[i].y * inv);
            *(bf16x2*)&H[b + i][2 * lane] = h;
        }
    }

    // ---- A-fragments; H then reused as f32 [16][68] scratch ----
    bf16x8 afr[4];
#pragma unroll
    for (int kb = 0; kb < 4; kb++)
        afr[kb] = *(const bf16x8*)&H[m][kb * 32 + q * 8];
    asm volatile("s_waitcnt lgkmcnt(0)" ::: "memory");

    float* Ef = (float*)&H[0][0];
    const int srow = lane >> 2;       // store row 0..15
    const int sc4 = (lane & 3) * 4;   // store col group
    f32x4 o[4];
#pragma unroll
    for (int nb = 0; nb < 4; nb++) o[nb] = (f32x4){0.f, 0.f, 0.f, 0.f};

#pragma unroll
    for (int half = 0; half < 2; half++) {
        // GEMM1 for this half's 64 emb cols + relu -> LDS f32 transpose
#pragma unroll
        for (int nb2 = 0; nb2 < 4; nb2++) {
            const int nb = half * 4 + nb2;
            f32x4 c = {0.f, 0.f, 0.f, 0.f};
#pragma unroll
            for (int kb = 0; kb < 4; kb++) {
                const bf16x8 b = *(const bf16x8*)(Wn_s + ((size_t)(nb * 4 + kb) * 64 + lane) * 8);
                c = __builtin_amdgcn_mfma_f32_16x16x32_bf16(afr[kb], b, c, 0, 0, 0);
            }
            const float bias = bn[nb * 16 + m];
#pragma unroll
            for (int r = 0; r < 4; r++)
                Ef[(q * 4 + r) * 68 + nb2 * 16 + m] = fmaxf(c[r] + bias, 0.f);
        }
        asm volatile("s_waitcnt lgkmcnt(0)" ::: "memory");  // transpose visible
        // coalesced emb stores (float4, 64 B runs)
#pragma unroll
        for (int it = 0; it < 4; it++) {
            const f32x4 v = *(const f32x4*)&Ef[srow * 68 + it * 16 + sc4];
            *(f32x4*)&emb[(size_t)(node0 + srow) * F + half * 64 + it * 16 + sc4] = v;
        }
        // GEMM2 partial accumulation over this half's 2 k-blocks
#pragma unroll
        for (int t2 = 0; t2 < 2; t2++) {
            const int kb = half * 2 + t2;
            const f32x4 f0 = *(const f32x4*)&Ef[m * 68 + t2 * 32 + q * 8];
            const f32x4 f1 = *(const f32x4*)&Ef[m * 68 + t2 * 32 + q * 8 + 4];
            bf16x8 a2f;
            a2f[0] = (__bf16)f0[0]; a2f[1] = (__bf16)f0[1];
            a2f[2] = (__bf16)f0[2]; a2f[3] = (__bf16)f0[3];
            a2f[4] = (__bf16)f1[0]; a2f[5] = (__bf16)f1[1];
            a2f[6] = (__bf16)f1[2]; a2f[7] = (__bf16)f1[3];
#pragma unroll
            for (int nb = 0; nb < 4; nb++) {
                const bf16x8 b = *(const bf16x8*)(Wo_s + ((size_t)(nb * 4 + kb) * 64 + lane) * 8);
                o[nb] = __builtin_amdgcn_mfma_f32_16x16x32_bf16(a2f, b, o[nb], 0, 0, 0);
            }
        }
        asm volatile("s_waitcnt lgkmcnt(0)" ::: "memory");  // reads done before overwrite
    }

    // ---- out epilogue: bias -> LDS f32 transpose -> coalesced stores ----
#pragma unroll
    for (int nb = 0; nb < 4; nb++) {
        const float bias = bo[nb * 16 + m];
#pragma unroll
        for (int r = 0; r < 4; r++)
            Ef[(q * 4 + r) * 68 + nb * 16 + m] = o[nb][r] + bias;
    }
    asm volatile("s_waitcnt lgkmcnt(0)" ::: "memory");
#pragma unroll
    for (int it = 0; it < 4; it++) {
        const f32x4 v = *(const f32x4*)&Ef[srow * 68 + it * 16 + sc4];
        *(f32x4*)&out[(size_t)(node0 + srow) * C_OUT + it * 16 + sc4] = v;
    }
}

// 4-edge gather step (fallback path only)
#define ACC4(bk, j, acc)                                                      \
    {                                                                         \
        const int4 s4 = *(const int4*)((bk) + (j));                           \
        const bf16x2 v0 = *(const bf16x2*)(xb + (size_t)s4.x * F + 2 * lane); \
        const bf16x2 v1 = *(const bf16x2*)(xb + (size_t)s4.y * F + 2 * lane); \
        const bf16x2 v2 = *(const bf16x2*)(xb + (size_t)s4.z * F + 2 * lane); \
        const bf16x2 v3 = *(const bf16x2*)(xb + (size_t)s4.w * F + 2 * lane); \
        acc.x += (float)v0.x + (float)v1.x + (float)v2.x + (float)v3.x;       \
        acc.y += (float)v0.y + (float)v1.y + (float)v2.y + (float)v3.y;       \
    }

#define ACC1(bk, j, acc)                                                       \
    {                                                                          \
        const int s = (bk)[j];                                                 \
        const bf16x2 v = *(const bf16x2*)(xb + (size_t)s * F + 2 * lane);      \
        acc.x += (float)v.x;                                                   \
        acc.y += (float)v.y;                                                   \
    }

// ---------------------------------------------------------------------------
// Fallback path (ws too small for xb): R5's proven two-kernel structure with
// xb aliased over the `out` region (dead before sage2 writes out).
// ---------------------------------------------------------------------------
__global__ __launch_bounds__(256, 8) void sage1_fb(const __bf16* __restrict__ xb,
                                                   const int* __restrict__ cnt,
                                                   const __bf16* __restrict__ Wn_s,
                                                   const float* __restrict__ bn,
                                                   float* emb) {
    __shared__ __align__(16) __bf16 Hs[4][16][136];
    const int w = threadIdx.x >> 6;
    const int lane = threadIdx.x & 63;
    const int node0 = (blockIdx.x * 4 + w) * 16;
    if (node0 >= N_NODES) return;
    const int q = lane >> 4, m = lane & 15;
    __bf16(*H)[136] = Hs[w];

    for (int i = 0; i < 16; i += 2) {
        const int nodeA = node0 + i, nodeB = nodeA + 1;
        const int degA = cnt[nodeA], degB = cnt[nodeB];
        const int nA = degA < CAP ? degA : CAP;
        const int nB = degB < CAP ? degB : CAP;
        const bf16x2 sA = *(const bf16x2*)(xb + (size_t)nodeA * F + 2 * lane);
        const bf16x2 sB = *(const bf16x2*)(xb + (size_t)nodeB * F + 2 * lane);
        float2 accA = make_float2((float)sA.x, (float)sA.y);
        float2 accB = make_float2((float)sB.x, (float)sB.y);
        const int* bkA = (const int*)(emb + (size_t)nodeA * F);
        const int* bkB = (const int*)(emb + (size_t)nodeB * F);
        int ja = 0, jb = 0;
        while ((ja + 4 <= nA) && (jb + 4 <= nB)) {
            ACC4(bkA, ja, accA);
            ACC4(bkB, jb, accB);
            ja += 4; jb += 4;
        }
        while (ja + 4 <= nA) { ACC4(bkA, ja, accA); ja += 4; }
        while (jb + 4 <= nB) { ACC4(bkB, jb, accB); jb += 4; }
        while ((ja < nA) && (jb < nB)) { ACC1(bkA, ja, accA); ACC1(bkB, jb, accB); ja++; jb++; }
        while (ja < nA) { ACC1(bkA, ja, accA); ja++; }
        while (jb < nB) { ACC1(bkB, jb, accB); jb++; }
        const float invA = 1.0f / (float)(degA + 1);
        const float invB = 1.0f / (float)(degB + 1);
        bf16x2 hA, hB;
        hA.x = (__bf16)(accA.x * invA); hA.y = (__bf16)(accA.y * invA);
        hB.x = (__bf16)(accB.x * invB); hB.y = (__bf16)(accB.y * invB);
        *(bf16x2*)&H[i][2 * lane] = hA;
        *(bf16x2*)&H[i + 1][2 * lane] = hB;
    }

    bf16x8 a[4];
#pragma unroll
    for (int kb = 0; kb < 4; kb++)
        a[kb] = *(const bf16x8*)&H[m][kb * 32 + q * 8];
    asm volatile("s_waitcnt lgkmcnt(0)" ::: "memory");

    float* Ef = (float*)&H[0][0];
    const int srow = lane >> 2;
    const int sc4 = (lane & 3) * 4;
#pragma unroll
    for (int half = 0; half < 2; half++) {
#pragma unroll
        for (int nb2 = 0; nb2 < 4; nb2++) {
            const int nb = half * 4 + nb2;
            f32x4 c = {0.f, 0.f, 0.f, 0.f};
#pragma unroll
            for (int kb = 0; kb < 4; kb++) {
                const bf16x8 b = *(const bf16x8*)(Wn_s + ((size_t)(nb * 4 + kb) * 64 + lane) * 8);
                c = __builtin_amdgcn_mfma_f32_16x16x32_bf16(a[kb], b, c, 0, 0, 0);
            }
            const float bias = bn[nb * 16 + m];
#pragma unroll
            for (int r = 0; r < 4; r++)
                Ef[(q * 4 + r) * 68 + nb2 * 16 + m] = fmaxf(c[r] + bias, 0.f);
        }
        asm volatile("s_waitcnt lgkmcnt(0)" ::: "memory");
#pragma unroll
        for (int it = 0; it < 4; it++) {
            const f32x4 v = *(const f32x4*)&Ef[srow * 68 + it * 16 + sc4];
            *(f32x4*)&emb[(size_t)(node0 + srow) * F + half * 64 + it * 16 + sc4] = v;
        }
        if (half == 0) asm volatile("s_waitcnt lgkmcnt(0)" ::: "memory");
    }
}

__global__ __launch_bounds__(256, 6) void sage2_fb(const float* __restrict__ emb,
                                                   const __bf16* __restrict__ Wo_s,
                                                   const float* __restrict__ bo,
                                                   float* __restrict__ out) {
    const int w = threadIdx.x >> 6;
    const int lane = threadIdx.x & 63;
    const int node0 = (blockIdx.x * 4 + w) * 16;
    if (node0 >= N_NODES) return;
    const int q = lane >> 4, m = lane & 15;

    bf16x8 a[4];
#pragma unroll
    for (int kb = 0; kb < 4; kb++) {
        const float* p = emb + (size_t)(node0 + m) * F + kb * 32 + q * 8;
        const float4 f0 = *(const float4*)(p);
        const float4 f1 = *(const float4*)(p + 4);
        bf16x8 v;
        v[0] = (__bf16)f0.x; v[1] = (__bf16)f0.y; v[2] = (__bf16)f0.z; v[3] = (__bf16)f0.w;
        v[4] = (__bf16)f1.x; v[5] = (__bf16)f1.y; v[6] = (__bf16)f1.z; v[7] = (__bf16)f1.w;
        a[kb] = v;
    }
#pragma unroll
    for (int nb = 0; nb < 4; nb++) {
        f32x4 c = {0.f, 0.f, 0.f, 0.f};
#pragma unroll
        for (int kb = 0; kb < 4; kb++) {
            const bf16x8 b = *(const bf16x8*)(Wo_s + ((size_t)(nb * 4 + kb) * 64 + lane) * 8);
            c = __builtin_amdgcn_mfma_f32_16x16x32_bf16(a[kb], b, c, 0, 0, 0);
        }
        const int col = nb * 16 + m;
        const float bias = bo[col];
#pragma unroll
        for (int r = 0; r < 4; r++) {
            const int node = node0 + q * 4 + r;
            out[(size_t)node * C_OUT + col] = c[r] + bias;
        }
    }
}

extern "C" void kernel_launch(void* const* d_in, const int* in_sizes, int n_in,
                              void* d_out, int out_size, void* d_ws, size_t ws_size,
                              hipStream_t stream) {
    const float* x  = (const float*)d_in[0];
    const int* src  = (const int*)d_in[1];
    const int* dst  = (const int*)d_in[2];
    const float* Wn = (const float*)d_in[3];
    const float* bn = (const float*)d_in[4];
    const float* Wo = (const float*)d_in[5];
    const float* bo = (const float*)d_in[6];

    float* out = (float*)d_out;                  // [N_NODES, 64] final output
    float* emb = out + (size_t)N_NODES * C_OUT;  // [N_NODES, 128] final output

    int* cnt = (int*)d_ws;                                   // 400,000 B
    __bf16* Wn_s = (__bf16*)((char*)d_ws + 400000);          // 32,768 B
    __bf16* Wo_s = Wn_s + 128 * 128;                         // 16,384 B
    __bf16* xb_ws = (__bf16*)((char*)d_ws + 449152);         // 100001 rows bf16

    const size_t WS_NEEDED = 449152 + (size_t)(N_NODES + 1) * F * 2;  // ~26.05 MB
    const bool fused = ws_size >= WS_NEEDED;  // constant across calls: graph-safe

    hipMemsetAsync(cnt, 0, N_NODES * sizeof(int), stream);

    if (fused) {
        prep<<<3125, 256, 0, stream>>>(x, src, dst, emb, cnt, Wn, Wo, Wn_s, Wo_s,
                                       xb_ws, 1);
        sage_fused<<<(N_NODES + 63) / 64, 256, 0, stream>>>(xb_ws, cnt, Wn_s, Wo_s,
                                                            bn, bo, out, emb);
    } else {
        __bf16* xb = (__bf16*)d_out;  // aliases `out` region (dead before sage2)
        prep<<<3125, 256, 0, stream>>>(x, src, dst, emb, cnt, Wn, Wo, Wn_s, Wo_s,
                                       xb, 0);
        sage1_fb<<<(N_NODES + 63) / 64, 256, 0, stream>>>(xb, cnt, Wn_s, bn, emb);
        sage2_fb<<<(N_NODES + 63) / 64, 256, 0, stream>>>(emb, Wo_s, bo, out);
    }
}